// Round 8
// baseline (616.762 us; speedup 1.0000x reference)
//
#include <hip/hip_runtime.h>
#include <hip/hip_bf16.h>
#include <math.h>

typedef short v8s __attribute__((ext_vector_type(8)));
typedef float v4f __attribute__((ext_vector_type(4)));
typedef unsigned int v4u __attribute__((ext_vector_type(4)));
typedef unsigned short us;
typedef unsigned int uu;

#define MFMA16(a,b,c) __builtin_amdgcn_mfma_f32_16x16x32_bf16((a),(b),(c),0,0,0)

// ---------------- workspace layout (fragment-linear, permuted-k) ----------
// Permutation (chunk t): slot (g,i) holds logical k = 32t + 16*(i>>2) + 4g + (i&3).
// Layer N's D registers repack in-lane into layer N+1's B-fragment.
// w3f: [t 7][nt3 13][lane 64][i 8]   A: j=16nt3+(l&15), k=perm(t,g,i)
// w2f: [nt 13][lane 64][i 8]         A: j=16nt+(l&15),  k=8g+i      (standard)
// w4f: [t*2+jt 14][lane 64][i 8]     A: j=16jt+(l&15),  k=perm(t,g,i)
#define W3F_ELEMS (7*13*512)
#define W2F_ELEMS (13*512)
#define W4F_ELEMS (14*512)
#define WALL_ELEMS (W3F_ELEMS + W2F_ELEMS + W4F_ELEMS)   // 60416 -> 120832 B
#define OFF_W3F 0
#define OFF_W2F (OFF_W3F + W3F_ELEMS*2)
#define OFF_W4F (OFF_W2F + W2F_ELEMS*2)
#define OFF_B2B (OFF_W4F + W4F_ELEMS*2)
#define OFF_B3B (OFF_B2B + 208*4)
#define OFF_B4B (OFF_B3B + 224*4)
#define OFF_W5B (OFF_B4B + 32*4)
#define OFF_W1P (OFF_W5B + 32*4)   // [96] f32: w1x[32] | w1y[32] | b1p[32]

__device__ __forceinline__ us f2bf(float f) {
    union { float f; unsigned int u; } v; v.f = f;
    unsigned int u = v.u + 0x7FFFu + ((v.u >> 16) & 1u);   // RNE
    return (us)(u >> 16);
}
// RNE pack via HW converter (compiler fuses to v_cvt_pk_bf16_f32)
__device__ __forceinline__ uu pack2bf(float a, float b) {
    union { __hip_bfloat162 v; uu u; } cv;
    cv.v.x = __float2bfloat16(a);
    cv.v.y = __float2bfloat16(b);
    return cv.u;
}

// ---------------- prep: fp32 weights -> bf16 fragment layout in ws --------
__global__ void prep_kernel(const float* __restrict__ w1, const float* __restrict__ b1,
                            const float* __restrict__ w2, const float* __restrict__ w3,
                            const float* __restrict__ w4, const float* __restrict__ b2,
                            const float* __restrict__ b3, const float* __restrict__ b4,
                            const float* __restrict__ w5, char* __restrict__ ws) {
    us* w3f = (us*)(ws + OFF_W3F);
    us* w2f = (us*)(ws + OFF_W2F);
    us* w4f = (us*)(ws + OFF_W4F);
    float* b2b = (float*)(ws + OFF_B2B);
    float* b3b = (float*)(ws + OFF_B3B);
    float* b4b = (float*)(ws + OFF_B4B);
    float* w5b = (float*)(ws + OFF_W5B);
    float* w1p = (float*)(ws + OFF_W1P);

    const int gid = blockIdx.x * blockDim.x + threadIdx.x;
    const int stride = gridDim.x * blockDim.x;

    for (int idx = gid; idx < W3F_ELEMS; idx += stride) {
        int i = idx & 7, lane = (idx >> 3) & 63, f = idx >> 9;
        int nt3 = f % 13, t = f / 13;
        int cc = lane & 15, gg = lane >> 4;
        int j = 16*nt3 + cc;
        int k = 32*t + 16*(i >> 2) + 4*gg + (i & 3);    // permuted-k
        w3f[idx] = f2bf((j < 200 && k < 200) ? w3[j*200 + k] : 0.f);
    }
    for (int idx = gid; idx < W2F_ELEMS; idx += stride) {
        int i = idx & 7, lane = (idx >> 3) & 63, nt = idx >> 9;
        int j = 16*nt + (lane & 15), k = 8*(lane >> 4) + i;   // standard k
        w2f[idx] = f2bf((j < 200 && k < 20) ? w2[j*20 + k] : 0.f);
    }
    for (int idx = gid; idx < W4F_ELEMS; idx += stride) {
        int i = idx & 7, lane = (idx >> 3) & 63, f = idx >> 9;
        int t = f >> 1, jt = f & 1;
        int cc = lane & 15, gg = lane >> 4;
        int j = 16*jt + cc;
        int k = 32*t + 16*(i >> 2) + 4*gg + (i & 3);    // permuted-k
        w4f[idx] = f2bf((j < 20 && k < 200) ? w4[j*200 + k] : 0.f);
    }
    for (int i = gid; i < 208; i += stride) b2b[i] = (i < 200) ? b2[i] : 0.f;
    for (int i = gid; i < 224; i += stride) b3b[i] = (i < 200) ? b3[i] : 0.f;
    for (int i = gid; i < 32;  i += stride) b4b[i] = (i < 20) ? b4[i] : 0.f;
    for (int i = gid; i < 32;  i += stride) w5b[i] = (i < 20) ? w5[i] : 0.f;
    for (int i = gid; i < 96;  i += stride) {
        int q = i >> 5, r = i & 31;
        float v = 0.f;
        if (r < 20) v = (q == 0) ? w1[2*r] : (q == 1) ? w1[2*r + 1] : b1[r];
        w1p[i] = v;
    }
}

// ---- wave-private gather: half-wave h takes neighbors 50h..50h+49;
//      lane's element is eoff = 32*(wv&1) + (lane&31). int2 idx loads (8B-aligned).
__device__ __forceinline__ void gather_issue(
    const int* __restrict__ nu, const int* __restrict__ ni,
    const float* __restrict__ uemb, const float* __restrict__ iemb,
    int eoff, float& su, float& si)
{
    float u0=0.f,u1=0.f,u2=0.f,u3=0.f, s0=0.f,s1=0.f,s2=0.f,s3=0.f;
    #pragma unroll
    for (int k = 0; k < 48; k += 4) {
        int2 ua = *(const int2*)(nu + k);
        int2 ub = *(const int2*)(nu + k + 2);
        int2 ia = *(const int2*)(ni + k);
        int2 ib = *(const int2*)(ni + k + 2);
        u0 += uemb[(size_t)ua.x*64 + eoff];
        u1 += uemb[(size_t)ua.y*64 + eoff];
        u2 += uemb[(size_t)ub.x*64 + eoff];
        u3 += uemb[(size_t)ub.y*64 + eoff];
        s0 += iemb[(size_t)ia.x*64 + eoff];
        s1 += iemb[(size_t)ia.y*64 + eoff];
        s2 += iemb[(size_t)ib.x*64 + eoff];
        s3 += iemb[(size_t)ib.y*64 + eoff];
    }
    int2 ut = *(const int2*)(nu + 48);
    int2 it = *(const int2*)(ni + 48);
    u0 += uemb[(size_t)ut.x*64 + eoff];
    u1 += uemb[(size_t)ut.y*64 + eoff];
    s0 += iemb[(size_t)it.x*64 + eoff];
    s1 += iemb[(size_t)it.y*64 + eoff];
    su = (u0+u1)+(u2+u3);
    si = (s0+s1)+(s2+s3);
}

// ---- layer 1 (2->20) per-lane redundant, straight into B-frag registers --
__device__ __forceinline__ void make_b1f(float su, float si, int c, int g,
                                         const float* __restrict__ w1p,
                                         v4u b1f[2])
{
    const float4 wx0 = *(const float4*)(w1p + 8*g);
    const float4 wx1 = *(const float4*)(w1p + 8*g + 4);
    const float4 wy0 = *(const float4*)(w1p + 32 + 8*g);
    const float4 wy1 = *(const float4*)(w1p + 32 + 8*g + 4);
    const float4 wb0 = *(const float4*)(w1p + 64 + 8*g);
    const float4 wb1 = *(const float4*)(w1p + 64 + 8*g + 4);
    #pragma unroll
    for (int m = 0; m < 2; ++m) {
        const float xu = __shfl(su, 16*m + c);
        const float xv = __shfl(si, 16*m + c);
        float h0 = fmaxf(fmaf(xu, wx0.x, fmaf(xv, wy0.x, wb0.x)), 0.f);
        float h1 = fmaxf(fmaf(xu, wx0.y, fmaf(xv, wy0.y, wb0.y)), 0.f);
        float h2 = fmaxf(fmaf(xu, wx0.z, fmaf(xv, wy0.z, wb0.z)), 0.f);
        float h3 = fmaxf(fmaf(xu, wx0.w, fmaf(xv, wy0.w, wb0.w)), 0.f);
        float h4 = fmaxf(fmaf(xu, wx1.x, fmaf(xv, wy1.x, wb1.x)), 0.f);
        float h5 = fmaxf(fmaf(xu, wx1.y, fmaf(xv, wy1.y, wb1.y)), 0.f);
        float h6 = fmaxf(fmaf(xu, wx1.z, fmaf(xv, wy1.z, wb1.z)), 0.f);
        float h7 = fmaxf(fmaf(xu, wx1.w, fmaf(xv, wy1.w, wb1.w)), 0.f);
        b1f[m] = (v4u){ pack2bf(h0,h1), pack2bf(h2,h3),
                        pack2bf(h4,h5), pack2bf(h6,h7) };
    }
}

// ---------------- persistent fused kernel ----------------
// Grid = 256 blocks (1/CU), 512 thr = 8 waves. All weight frags staged to LDS
// ONCE; each block loops over NG batch-groups of 4 rows x 64 e with wave-private
// gather, bias-as-C-in MFMAs, 1 barrier/group (mbuf exchange only).
__global__ __launch_bounds__(512, 2) void fused_kernel(
    const int* __restrict__ user_idxs, const int* __restrict__ item_idxs,
    const int* __restrict__ uidx, const int* __restrict__ iidx,
    const float* __restrict__ uemb, const float* __restrict__ iemb,
    const float* __restrict__ b5p, const char* __restrict__ ws,
    float* __restrict__ out, int B, int NG)
{
    __shared__ us wall[WALL_ELEMS];     // 120832 B : w3f | w2f | w4f
    __shared__ float mbuf[2][8];        // per-wave partial sums, double-buffered

    const int tid  = (int)threadIdx.x;
    const int lane = tid & 63;
    const int wv   = __builtin_amdgcn_readfirstlane(tid >> 6);
    const int c = lane & 15;
    const int g = lane >> 4;
    const int h = lane >> 5;                        // half-wave id
    const int eoff = 32*(wv & 1) + (lane & 31);     // this lane's e
    const int bl = wv >> 1;                         // batch row within group
    const int gstr = (int)gridDim.x << 2;           // batch rows per group step

    // ---- stage all weight fragments to LDS once --------------------------
    {
        const us* src = (const us*)(ws + OFF_W3F);
        for (int s = tid; s < WALL_ELEMS/8; s += 512)
            *(v8s*)(wall + s*8) = *(const v8s*)(src + s*8);
    }
    const us* w3l = wall;
    const us* w2l = wall + W3F_ELEMS;
    const us* w4l = wall + W3F_ELEMS + W2F_ELEMS;
    const float* b2b = (const float*)(ws + OFF_B2B);
    const float* b3b = (const float*)(ws + OFF_B3B);
    const float* b4b = (const float*)(ws + OFF_B4B);
    const float* w5b = (const float*)(ws + OFF_W5B);
    const float* w1p = (const float*)(ws + OFF_W1P);
    const float b5v = b5p[0];

    // ---- gather group 0 ----------------------------------------------------
    float su, si;
    {
        int b = (int)blockIdx.x*4 + bl; if (b >= B) b = B - 1;
        const int* nu = uidx + (size_t)user_idxs[b]*100 + h*50;
        const int* ni = iidx + (size_t)item_idxs[b]*100 + h*50;
        gather_issue(nu, ni, uemb, iemb, eoff, su, si);
    }
    su += __shfl_xor(su, 32);
    si += __shfl_xor(si, 32);
    __syncthreads();                                 // weights staged
    v4u b1f[2];
    make_b1f(su, si, c, g, w1p, b1f);

    #pragma unroll 1
    for (int gp = 0; gp < NG; ++gp) {
        const v8s bb0 = __builtin_bit_cast(v8s, b1f[0]);
        const v8s bb1 = __builtin_bit_cast(v8s, b1f[1]);

        // ---- Layer 2 (20->200): paired nt, bias as C-in, repack at once ----
        v4u b2f[2][7];
        #pragma unroll
        for (int t = 0; t < 6; ++t) {
            v8s afa = *(const v8s*)(w2l + ((2*t)*64   + lane)*8);
            v8s afb = *(const v8s*)(w2l + ((2*t+1)*64 + lane)*8);
            v4f bva = *(const v4f*)(b2b + 32*t + 4*g);
            v4f bvb = *(const v4f*)(b2b + 32*t + 16 + 4*g);
            v4f aa0 = MFMA16(afa, bb0, bva);
            v4f aa1 = MFMA16(afa, bb1, bva);
            v4f ab0 = MFMA16(afb, bb0, bvb);
            v4f ab1 = MFMA16(afb, bb1, bvb);
            b2f[0][t] = (v4u){ pack2bf(fmaxf(aa0[0],0.f), fmaxf(aa0[1],0.f)),
                               pack2bf(fmaxf(aa0[2],0.f), fmaxf(aa0[3],0.f)),
                               pack2bf(fmaxf(ab0[0],0.f), fmaxf(ab0[1],0.f)),
                               pack2bf(fmaxf(ab0[2],0.f), fmaxf(ab0[3],0.f)) };
            b2f[1][t] = (v4u){ pack2bf(fmaxf(aa1[0],0.f), fmaxf(aa1[1],0.f)),
                               pack2bf(fmaxf(aa1[2],0.f), fmaxf(aa1[3],0.f)),
                               pack2bf(fmaxf(ab1[0],0.f), fmaxf(ab1[1],0.f)),
                               pack2bf(fmaxf(ab1[2],0.f), fmaxf(ab1[3],0.f)) };
        }
        {   // t = 6: nt = 12 only; upper k-half zero (pad)
            v8s afa = *(const v8s*)(w2l + (12*64 + lane)*8);
            v4f bva = *(const v4f*)(b2b + 192 + 4*g);
            v4f aa0 = MFMA16(afa, bb0, bva);
            v4f aa1 = MFMA16(afa, bb1, bva);
            b2f[0][6] = (v4u){ pack2bf(fmaxf(aa0[0],0.f), fmaxf(aa0[1],0.f)),
                               pack2bf(fmaxf(aa0[2],0.f), fmaxf(aa0[3],0.f)), 0u, 0u };
            b2f[1][6] = (v4u){ pack2bf(fmaxf(aa1[0],0.f), fmaxf(aa1[1],0.f)),
                               pack2bf(fmaxf(aa1[2],0.f), fmaxf(aa1[3],0.f)), 0u, 0u };
        }

        // ---- issue next group's gather (hidden under L3/L4) ----------------
        float nsu = 0.f, nsi = 0.f;
        if (gp + 1 < NG) {
            int b = (gp + 1)*gstr + (int)blockIdx.x*4 + bl; if (b >= B) b = B - 1;
            const int* nu = uidx + (size_t)user_idxs[b]*100 + h*50;
            const int* ni = iidx + (size_t)item_idxs[b]*100 + h*50;
            gather_issue(nu, ni, uemb, iemb, eoff, nsu, nsi);
        }

        // ---- Layer 3 (200->200): 7 chunks, no barriers, bias C-in at ksc=0 -
        v4f acc3[2][13];
        #pragma unroll
        for (int nt = 0; nt < 13; ++nt) {
            v8s af = *(const v8s*)(w3l + (nt*64 + lane)*8);       // chunk 0
            v4f bv = *(const v4f*)(b3b + 16*nt + 4*g);
            acc3[0][nt] = MFMA16(af, __builtin_bit_cast(v8s, b2f[0][0]), bv);
            acc3[1][nt] = MFMA16(af, __builtin_bit_cast(v8s, b2f[1][0]), bv);
        }
        #pragma unroll
        for (int ksc = 1; ksc < 7; ++ksc) {
            v8s bm0 = __builtin_bit_cast(v8s, b2f[0][ksc]);
            v8s bm1 = __builtin_bit_cast(v8s, b2f[1][ksc]);
            #pragma unroll
            for (int nt = 0; nt < 13; ++nt) {
                v8s af = *(const v8s*)(w3l + ((ksc*13 + nt)*64 + lane)*8);
                acc3[0][nt] = MFMA16(af, bm0, acc3[0][nt]);
                acc3[1][nt] = MFMA16(af, bm1, acc3[1][nt]);
            }
        }

        // ---- Layer 4 (200->20) fused with L3 epilogue; bias C-in at t=0 ----
        v4f acc4[2][2];
        v4f bc0 = *(const v4f*)(b4b + 4*g);
        v4f bc1 = *(const v4f*)(b4b + 16 + 4*g);
        #pragma unroll
        for (int t = 0; t < 7; ++t) {
            v8s a40 = *(const v8s*)(w4l + ((2*t)*64   + lane)*8);
            v8s a41 = *(const v8s*)(w4l + ((2*t+1)*64 + lane)*8);
            #pragma unroll
            for (int m = 0; m < 2; ++m) {
                v4u bfu;
                if (t < 6) {
                    bfu = (v4u){
                        pack2bf(fmaxf(acc3[m][2*t][0],0.f),   fmaxf(acc3[m][2*t][1],0.f)),
                        pack2bf(fmaxf(acc3[m][2*t][2],0.f),   fmaxf(acc3[m][2*t][3],0.f)),
                        pack2bf(fmaxf(acc3[m][2*t+1][0],0.f), fmaxf(acc3[m][2*t+1][1],0.f)),
                        pack2bf(fmaxf(acc3[m][2*t+1][2],0.f), fmaxf(acc3[m][2*t+1][3],0.f)) };
                } else {
                    bfu = (v4u){
                        pack2bf(fmaxf(acc3[m][12][0],0.f), fmaxf(acc3[m][12][1],0.f)),
                        pack2bf(fmaxf(acc3[m][12][2],0.f), fmaxf(acc3[m][12][3],0.f)),
                        0u, 0u };
                }
                v8s bb = __builtin_bit_cast(v8s, bfu);
                acc4[m][0] = MFMA16(a40, bb, (t == 0) ? bc0 : acc4[m][0]);
                acc4[m][1] = MFMA16(a41, bb, (t == 0) ? bc1 : acc4[m][1]);
            }
        }

        // ---- Layer 5 (20->1) dot + full-wave reduce over 32 rows ------------
        v4f w5lo = *(const v4f*)(w5b + 4*g);
        v4f w5hi = *(const v4f*)(w5b + 16 + 4*g);
        float s = 0.f;
        #pragma unroll
        for (int m = 0; m < 2; ++m) {
            #pragma unroll
            for (int q = 0; q < 4; ++q) {
                float h0 = fmaxf(acc4[m][0][q], 0.f);   // bias already in acc
                float h1 = fmaxf(acc4[m][1][q], 0.f);
                s = fmaf(h0, w5lo[q], fmaf(h1, w5hi[q], s));
            }
        }
        #pragma unroll
        for (int off = 1; off < 64; off <<= 1) s += __shfl_xor(s, off);
        if (lane == 0) mbuf[gp & 1][wv] = s;
        __syncthreads();                      // the only barrier in the group
        if (tid < 4) {
            int b = gp*gstr + (int)blockIdx.x*4 + tid;
            if (b < B) {
                float v = (mbuf[gp & 1][2*tid] + mbuf[gp & 1][2*tid + 1])
                          * (1.0f / 64.0f) + b5v;
                out[b] = 1.0f / (1.0f + expf(-v));
            }
        }

        // ---- finish next gather -> b1f for next iteration -------------------
        if (gp + 1 < NG) {
            nsu += __shfl_xor(nsu, 32);
            nsi += __shfl_xor(nsi, 32);
            make_b1f(nsu, nsi, c, g, w1p, b1f);
        }
    }
}

extern "C" void kernel_launch(void* const* d_in, const int* in_sizes, int n_in,
                              void* d_out, int out_size, void* d_ws, size_t ws_size,
                              hipStream_t stream) {
    const int*   user_idxs = (const int*)d_in[0];
    const int*   item_idxs = (const int*)d_in[1];
    const int*   uidx      = (const int*)d_in[2];
    const int*   iidx      = (const int*)d_in[3];
    const float* uemb      = (const float*)d_in[4];
    const float* iemb      = (const float*)d_in[5];
    const float* w1 = (const float*)d_in[6];
    const float* b1 = (const float*)d_in[7];
    const float* w2 = (const float*)d_in[8];
    const float* b2 = (const float*)d_in[9];
    const float* w3 = (const float*)d_in[10];
    const float* b3 = (const float*)d_in[11];
    const float* w4 = (const float*)d_in[12];
    const float* b4 = (const float*)d_in[13];
    const float* w5 = (const float*)d_in[14];
    const float* b5 = (const float*)d_in[15];
    float* out = (float*)d_out;
    char* ws = (char*)d_ws;

    const int B = in_sizes[0];

    hipLaunchKernelGGL(prep_kernel, dim3(256), dim3(256), 0, stream,
                       w1, b1, w2, w3, w4, b2, b3, b4, w5, ws);

    const int GRID = 256;
    const int rows_per_group = GRID * 4;
    const int NG = (B + rows_per_group - 1) / rows_per_group;
    hipLaunchKernelGGL(fused_kernel, dim3(GRID), dim3(512), 0, stream,
                       user_idxs, item_idxs, uidx, iidx, uemb, iemb,
                       b5, ws, out, B, NG);
}